// Round 5
// baseline (363.726 us; speedup 1.0000x reference)
//
#include <hip/hip_runtime.h>

#define TPB 256

typedef __attribute__((ext_vector_type(8))) short          bf8_t;   // 8 x bf16 (4 VGPRs)
typedef __attribute__((ext_vector_type(8))) unsigned short us8_t;
typedef __attribute__((ext_vector_type(4))) float          f4_t;
typedef __attribute__((ext_vector_type(4))) unsigned short us4_t;

__device__ __forceinline__ unsigned short f2bf(float f) {
    union { float f; unsigned u; } v; v.f = f;
    unsigned r = v.u + 0x7FFFu + ((v.u >> 16) & 1u);   // round-to-nearest-even
    return (unsigned short)(r >> 16);
}
__device__ __forceinline__ float bf2f(unsigned short u) {
    union { unsigned u; float f; } v; v.u = (unsigned)u << 16; return v.f;
}

// ---------------- graph build (CSR by dst, rebuilt every call) ----------------

__global__ void k_count(const int* __restrict__ ei, int E, int* __restrict__ cnt) {
    int e = blockIdx.x * TPB + threadIdx.x;
    if (e < E) atomicAdd(&cnt[ei[E + e]], 1);
}

__global__ void k_blocksum(const int* __restrict__ cnt, int n, int* __restrict__ bsum) {
    __shared__ int s[TPB];
    int t = threadIdx.x, i = blockIdx.x * TPB + t;
    s[t] = (i < n) ? cnt[i] : 0;
    __syncthreads();
    for (int off = TPB / 2; off > 0; off >>= 1) {
        if (t < off) s[t] += s[t + off];
        __syncthreads();
    }
    if (t == 0) bsum[blockIdx.x] = s[0];
}

__global__ void k_scan_bsum(int* __restrict__ bsum, int nb) {
    __shared__ int s[512];
    int t = threadIdx.x;
    int v = (t < nb) ? bsum[t] : 0;
    s[t] = v; __syncthreads();
    for (int off = 1; off < 512; off <<= 1) {
        int x = (t >= off) ? s[t - off] : 0;
        __syncthreads();
        s[t] += x;
        __syncthreads();
    }
    if (t < nb) bsum[t] = s[t] - v;   // exclusive block offsets
}

__global__ void k_rowptr(const int* __restrict__ cnt, const int* __restrict__ bsum, int n, int E,
                         int* __restrict__ rowptr, int* __restrict__ cursor,
                         float* __restrict__ dinv, float* __restrict__ dis) {
    __shared__ int s[TPB];
    int t = threadIdx.x, i = blockIdx.x * TPB + t;
    int v = (i < n) ? cnt[i] : 0;
    s[t] = v; __syncthreads();
    for (int off = 1; off < TPB; off <<= 1) {
        int x = (t >= off) ? s[t - off] : 0;
        __syncthreads();
        s[t] += x;
        __syncthreads();
    }
    if (i < n) {
        int start = bsum[blockIdx.x] + s[t] - v;
        rowptr[i] = start;
        cursor[i] = start;
        float d = (float)(v + 1);      // + self loop; deg >= 1 always
        dinv[i] = 1.0f / d;
        dis[i]  = rsqrtf(d);
    }
    if (i == 0) rowptr[n] = E;
}

__global__ void k_fill(const int* __restrict__ ei, int E,
                       int* __restrict__ cursor, int* __restrict__ col) {
    int e = blockIdx.x * TPB + threadIdx.x;
    if (e < E) {
        int src = ei[e], dst = ei[E + e];
        int p = atomicAdd(&cursor[dst], 1);
        col[p] = src;
    }
}

// ---------------- weight transpose+convert: T[m*K + k] = bf16(W[k*M + m]) ----------------
__global__ void k_wconv(const float* W1, const float* Wr1, const float* W2, const float* Wr2,
                        const float* Wmu, const float* Wls,
                        unsigned short* T1, unsigned short* Tr1, unsigned short* T2,
                        unsigned short* Tr2, unsigned short* Tmu, unsigned short* Tls) {
    const float* W; unsigned short* T; int K, M;
    switch (blockIdx.y) {
        case 0: W = W1;  T = T1;  K = 128; M = 96; break;
        case 1: W = Wr1; T = Tr1; K = 128; M = 96; break;
        case 2: W = W2;  T = T2;  K = 96;  M = 64; break;
        case 3: W = Wr2; T = Tr2; K = 96;  M = 64; break;
        case 4: W = Wmu; T = Tmu; K = 64;  M = 32; break;
        default:W = Wls; T = Tls; K = 64;  M = 32; break;
    }
    int idx = blockIdx.x * TPB + threadIdx.x;
    if (idx < K * M) {
        int m = idx / K, k = idx % K;
        T[idx] = f2bf(W[k * M + m]);
    }
}

// ---------------- MFMA GEMM v7: NO LDS — B read directly from L2-resident global --------------
// Occupancy evidence across rounds: 52 KB LDS kernels pin at Occ ~13% = ONE 4-wave block/CU
// (usable LDS is ~96 KB here, so 2x52 KB doesn't fit); 26 KB LDS kernel reached 43%.
// B (49/24/8 KB) is read by every block -> perfectly L2-cached broadcast data. So drop LDS
// entirely: each lane loads its B fragment straight from WT with the same indexing the
// ds_read used (16-B loads; per instruction 16 rows x 64-B sectors -> clean L2 transactions).
// No staging phase, no __syncthreads, no bank conflicts; occupancy now VGPR-limited:
// <=128 VGPR -> 4 blocks/CU -> all ~782 blocks resident at once (capacity 1024).
// Keeps: full-M rows per block (r1 traffic lesson), 2-tile pairs sharing B regs (halves
// B-load rate), swapped-operand MFMA (row-contiguous us4 stores).
template <int K, int M, int MINW, bool AF32>
__global__ __launch_bounds__(TPB, MINW) void k_gemm7(const void* __restrict__ Av,
                                                     const unsigned short* __restrict__ WT,
                                                     unsigned short* __restrict__ Yb,
                                                     int n, int np) {
    constexpr int KS = K / 32;

    int lane = threadIdx.x & 63;
    int wave = threadIdx.x >> 6;
    int quad = lane >> 4;
    int l15  = lane & 15;

    for (int pair = blockIdx.x; pair < np; pair += gridDim.x) {
        int base0 = pair * 128 + wave * 16;
        int base1 = base0 + 64;
        int row0 = base0 + l15;                 // this lane's output row (tile 0)
        int row1 = base1 + l15;
        int rA0 = row0 > n - 1 ? n - 1 : row0;  // clamped for loads only
        int rA1 = row1 > n - 1 ? n - 1 : row1;

        bf8_t a0[KS], a1[KS];
        if (AF32) {
            const float* ap0 = (const float*)Av + (size_t)rA0 * K + quad * 8;
            const float* ap1 = (const float*)Av + (size_t)rA1 * K + quad * 8;
#pragma unroll
            for (int s = 0; s < KS; s++) {
                f4_t lo0 = *(const f4_t*)(ap0 + s * 32);
                f4_t hi0 = *(const f4_t*)(ap0 + s * 32 + 4);
                f4_t lo1 = *(const f4_t*)(ap1 + s * 32);
                f4_t hi1 = *(const f4_t*)(ap1 + s * 32 + 4);
                bf8_t t0, t1;
                t0[0] = (short)f2bf(lo0.x); t0[1] = (short)f2bf(lo0.y);
                t0[2] = (short)f2bf(lo0.z); t0[3] = (short)f2bf(lo0.w);
                t0[4] = (short)f2bf(hi0.x); t0[5] = (short)f2bf(hi0.y);
                t0[6] = (short)f2bf(hi0.z); t0[7] = (short)f2bf(hi0.w);
                t1[0] = (short)f2bf(lo1.x); t1[1] = (short)f2bf(lo1.y);
                t1[2] = (short)f2bf(lo1.z); t1[3] = (short)f2bf(lo1.w);
                t1[4] = (short)f2bf(hi1.x); t1[5] = (short)f2bf(hi1.y);
                t1[6] = (short)f2bf(hi1.z); t1[7] = (short)f2bf(hi1.w);
                a0[s] = t0; a1[s] = t1;
            }
        } else {
            const unsigned short* ap0 = (const unsigned short*)Av + (size_t)rA0 * K + quad * 8;
            const unsigned short* ap1 = (const unsigned short*)Av + (size_t)rA1 * K + quad * 8;
#pragma unroll
            for (int s = 0; s < KS; s++) { a0[s] = *(const bf8_t*)(ap0 + s * 32);
                                           a1[s] = *(const bf8_t*)(ap1 + s * 32); }
        }

#pragma unroll
        for (int ct = 0; ct < M / 16; ct++) {
            const unsigned short* bp = WT + (size_t)(ct * 16 + l15) * K + quad * 8;
            f4_t acc0 = {0.f, 0.f, 0.f, 0.f};
            f4_t acc1 = {0.f, 0.f, 0.f, 0.f};
#pragma unroll
            for (int s = 0; s < KS; s++) {
                bf8_t b = *(const bf8_t*)(bp + s * 32);
                acc0 = __builtin_amdgcn_mfma_f32_16x16x32_bf16(b, a0[s], acc0, 0, 0, 0);
                acc1 = __builtin_amdgcn_mfma_f32_16x16x32_bf16(b, a1[s], acc1, 0, 0, 0);
            }
            int col0 = ct * 16 + quad * 4;      // 4 consecutive output cols per lane
            us4_t o0, o1;
#pragma unroll
            for (int r = 0; r < 4; r++) { o0[r] = f2bf(acc0[r]); o1[r] = f2bf(acc1[r]); }
            if (row0 < n) *(us4_t*)(Yb + (size_t)row0 * M + col0) = o0;
            if (row1 < n) *(us4_t*)(Yb + (size_t)row1 * M + col0) = o1;
        }
    }
}

// ---------------- head GEMM v7: out = Z @ [Wmu|Wls] + bias, fp32 f4 stores, no LDS ----------
__global__ __launch_bounds__(TPB, 4) void k_gemm_out7(const unsigned short* __restrict__ Z,
                                                      const unsigned short* __restrict__ WT,
                                                      const float* __restrict__ bmu,
                                                      const float* __restrict__ bls,
                                                      float* __restrict__ out, int n, int np) {
    constexpr int K = 64, M = 64, KS = 2;

    int lane = threadIdx.x & 63;
    int wave = threadIdx.x >> 6;
    int quad = lane >> 4;
    int l15  = lane & 15;

    for (int pair = blockIdx.x; pair < np; pair += gridDim.x) {
        int base0 = pair * 128 + wave * 16;
        int base1 = base0 + 64;
        int row0 = base0 + l15;
        int row1 = base1 + l15;
        int rA0 = row0 > n - 1 ? n - 1 : row0;
        int rA1 = row1 > n - 1 ? n - 1 : row1;
        const unsigned short* ap0 = Z + (size_t)rA0 * K + quad * 8;
        const unsigned short* ap1 = Z + (size_t)rA1 * K + quad * 8;
        bf8_t a0[KS], a1[KS];
#pragma unroll
        for (int s = 0; s < KS; s++) { a0[s] = *(const bf8_t*)(ap0 + s * 32);
                                       a1[s] = *(const bf8_t*)(ap1 + s * 32); }

#pragma unroll
        for (int ct = 0; ct < M / 16; ct++) {
            const unsigned short* bp = WT + (size_t)(ct * 16 + l15) * K + quad * 8;
            f4_t acc0 = {0.f, 0.f, 0.f, 0.f};
            f4_t acc1 = {0.f, 0.f, 0.f, 0.f};
#pragma unroll
            for (int s = 0; s < KS; s++) {
                bf8_t b = *(const bf8_t*)(bp + s * 32);
                acc0 = __builtin_amdgcn_mfma_f32_16x16x32_bf16(b, a0[s], acc0, 0, 0, 0);
                acc1 = __builtin_amdgcn_mfma_f32_16x16x32_bf16(b, a1[s], acc1, 0, 0, 0);
            }
            int col0 = ct * 16 + quad * 4;     // ct<2 -> mu cols, ct>=2 -> ls cols
            f4_t bv = *(const f4_t*)(((col0 < 32) ? bmu : (bls - 32)) + col0);
            f4_t o0, o1;
#pragma unroll
            for (int r = 0; r < 4; r++) { o0[r] = acc0[r] + bv[r]; o1[r] = acc1[r] + bv[r]; }
            size_t cb = (col0 < 32) ? (size_t)col0 : ((size_t)n * 32 + (col0 - 32));
            if (row0 < n) *(f4_t*)(out + cb + (size_t)row0 * 32) = o0;
            if (row1 < n) *(f4_t*)(out + cb + (size_t)row1 * 32) = o1;
        }
    }
}

// ---------------- ClusterGCN aggregation (bf16 in/out) ----------------
// AB: n x 2*MF bf16 rows [y | r].  Hb[i] = bf16( s * relu( dinv[i]*(sum_{src->i} y[src] + y[i])
//                                                          + r[i] + bias ) ),  s = SCALE?dis[i]:1
template <int MF, int GRP, bool SCALE>
__global__ __launch_bounds__(TPB) void k_aggc(const unsigned short* __restrict__ AB,
                                              const float* __restrict__ bias,
                                              const float* __restrict__ dinv,
                                              const float* __restrict__ dis,
                                              const int* __restrict__ rowptr,
                                              const int* __restrict__ col,
                                              unsigned short* __restrict__ Hb, int n) {
    constexpr int LD = 2 * MF;
    int g = blockIdx.x * (TPB / GRP) + threadIdx.x / GRP;
    int l = threadIdx.x & (GRP - 1);
    if (g >= n) return;
    int c = l * 8;
    if (c >= MF) return;
    int r0 = rowptr[g], r1 = rowptr[g + 1];
    float acc[8];
    {
        bf8_t v = *(const bf8_t*)(AB + (size_t)g * LD + c);
#pragma unroll
        for (int j = 0; j < 8; j++) acc[j] = bf2f((unsigned short)v[j]);
    }
    int e = r0;
    for (; e + 4 <= r1; e += 4) {          // 4-way MLP unroll
        int s0 = col[e], s1 = col[e + 1], s2 = col[e + 2], s3 = col[e + 3];
        bf8_t v0 = *(const bf8_t*)(AB + (size_t)s0 * LD + c);
        bf8_t v1 = *(const bf8_t*)(AB + (size_t)s1 * LD + c);
        bf8_t v2 = *(const bf8_t*)(AB + (size_t)s2 * LD + c);
        bf8_t v3 = *(const bf8_t*)(AB + (size_t)s3 * LD + c);
#pragma unroll
        for (int j = 0; j < 8; j++)
            acc[j] += (bf2f((unsigned short)v0[j]) + bf2f((unsigned short)v1[j]))
                    + (bf2f((unsigned short)v2[j]) + bf2f((unsigned short)v3[j]));
    }
    for (; e < r1; ++e) {
        int s = col[e];
        bf8_t v = *(const bf8_t*)(AB + (size_t)s * LD + c);
#pragma unroll
        for (int j = 0; j < 8; j++) acc[j] += bf2f((unsigned short)v[j]);
    }
    float di = dinv[g];
    float sc = SCALE ? dis[g] : 1.0f;
    bf8_t rr = *(const bf8_t*)(AB + (size_t)g * LD + MF + c);
    us8_t o;
#pragma unroll
    for (int j = 0; j < 8; j++) {
        float h = fmaxf(acc[j] * di + bf2f((unsigned short)rr[j]) + bias[c + j], 0.f);
        o[j] = f2bf(SCALE ? sc * h : h);
    }
    *(us8_t*)(Hb + (size_t)g * MF + c) = o;
}

// ---------------- head aggregation: Z[g] = bf16( dis[g] * (sum_{src->g} H2s[src] + H2s[g]) ) ----
// H2s rows are pre-scaled by dis (written by layer-2 epilogue), so no per-edge dis load.
__global__ __launch_bounds__(TPB) void k_agghead(const unsigned short* __restrict__ H2s,
                                                 const float* __restrict__ dis,
                                                 const int* __restrict__ rowptr,
                                                 const int* __restrict__ col,
                                                 unsigned short* __restrict__ Z, int n) {
    const int GRP = 8;
    int g = blockIdx.x * (TPB / GRP) + threadIdx.x / GRP;
    int l = threadIdx.x & (GRP - 1);
    if (g >= n) return;
    int c = l * 8;
    int r0 = rowptr[g], r1 = rowptr[g + 1];
    float acc[8];
    {
        bf8_t v = *(const bf8_t*)(H2s + (size_t)g * 64 + c);
#pragma unroll
        for (int j = 0; j < 8; j++) acc[j] = bf2f((unsigned short)v[j]);
    }
    int e = r0;
    for (; e + 4 <= r1; e += 4) {
        int s0 = col[e], s1 = col[e + 1], s2 = col[e + 2], s3 = col[e + 3];
        bf8_t v0 = *(const bf8_t*)(H2s + (size_t)s0 * 64 + c);
        bf8_t v1 = *(const bf8_t*)(H2s + (size_t)s1 * 64 + c);
        bf8_t v2 = *(const bf8_t*)(H2s + (size_t)s2 * 64 + c);
        bf8_t v3 = *(const bf8_t*)(H2s + (size_t)s3 * 64 + c);
#pragma unroll
        for (int j = 0; j < 8; j++)
            acc[j] += (bf2f((unsigned short)v0[j]) + bf2f((unsigned short)v1[j]))
                    + (bf2f((unsigned short)v2[j]) + bf2f((unsigned short)v3[j]));
    }
    for (; e < r1; ++e) {
        int s = col[e];
        bf8_t v = *(const bf8_t*)(H2s + (size_t)s * 64 + c);
#pragma unroll
        for (int j = 0; j < 8; j++) acc[j] += bf2f((unsigned short)v[j]);
    }
    float dg = dis[g];
    us8_t o;
#pragma unroll
    for (int j = 0; j < 8; j++) o[j] = f2bf(dg * acc[j]);
    *(us8_t*)(Z + (size_t)g * 64 + c) = o;
}

// ---------------- launch ----------------

extern "C" void kernel_launch(void* const* d_in, const int* in_sizes, int n_in,
                              void* d_out, int out_size, void* d_ws, size_t ws_size,
                              hipStream_t stream) {
    const float* x   = (const float*)d_in[0];
    const int*   ei  = (const int*)d_in[1];
    const float* W1  = (const float*)d_in[2];
    const float* b1  = (const float*)d_in[3];
    const float* Wr1 = (const float*)d_in[4];
    const float* W2  = (const float*)d_in[5];
    const float* b2  = (const float*)d_in[6];
    const float* Wr2 = (const float*)d_in[7];
    const float* Wmu = (const float*)d_in[8];
    const float* bmu = (const float*)d_in[9];
    const float* Wls = (const float*)d_in[10];
    const float* bls = (const float*)d_in[11];
    float* out = (float*)d_out;

    const int IN = 128, L1F = 96, L2F = 64;
    const int N = in_sizes[0] / IN;
    const int E = in_sizes[1] / 2;

    char* ws = (char*)d_ws;
    size_t off = 0;
    auto alloc = [&](size_t b) { size_t r = off; off += (b + 255) & ~(size_t)255; return r; };

    const int nb = (N + TPB - 1) / TPB;
    int*   cnt  = (int*)(ws + alloc((size_t)N * 4));
    int*   bsum = (int*)(ws + alloc((size_t)nb * 4));
    int*   rowp = (int*)(ws + alloc((size_t)(N + 1) * 4));
    int*   curs = (int*)(ws + alloc((size_t)N * 4));
    int*   col  = (int*)(ws + alloc((size_t)E * 4));
    float* dinv = (float*)(ws + alloc((size_t)N * 4));
    float* dis  = (float*)(ws + alloc((size_t)N * 4));
    // weight blocks allocated contiguously -> concatenated [W|Wr] views (all sizes %256==0)
    unsigned short* T1  = (unsigned short*)(ws + alloc((size_t)IN  * L1F * 2));
    unsigned short* Tr1 = (unsigned short*)(ws + alloc((size_t)IN  * L1F * 2));
    unsigned short* T2  = (unsigned short*)(ws + alloc((size_t)L1F * L2F * 2));
    unsigned short* Tr2 = (unsigned short*)(ws + alloc((size_t)L1F * L2F * 2));
    unsigned short* Tmu = (unsigned short*)(ws + alloc((size_t)L2F * 32 * 2));
    unsigned short* Tls = (unsigned short*)(ws + alloc((size_t)L2F * 32 * 2));
    unsigned short* AB1 = (unsigned short*)(ws + alloc((size_t)N * 2 * L1F * 2)); // N x 192 bf16
    unsigned short* AB2 = (unsigned short*)(ws + alloc((size_t)N * 2 * L2F * 2)); // N x 128 bf16
    unsigned short* Hb1 = (unsigned short*)(ws + alloc((size_t)N * L1F * 2));     // relu'd h1
    unsigned short* H2s = (unsigned short*)(ws + alloc((size_t)N * L2F * 2));     // dis-scaled h2
    unsigned short* Zag = (unsigned short*)(ws + alloc((size_t)N * L2F * 2));     // aggregated head input

    hipMemsetAsync(cnt, 0, (size_t)N * 4, stream);

    dim3 eg((E + TPB - 1) / TPB);
    k_count<<<eg, TPB, 0, stream>>>(ei, E, cnt);
    k_blocksum<<<nb, TPB, 0, stream>>>(cnt, N, bsum);
    k_scan_bsum<<<1, 512, 0, stream>>>(bsum, nb);
    k_rowptr<<<nb, TPB, 0, stream>>>(cnt, bsum, N, E, rowp, curs, dinv, dis);
    k_fill<<<eg, TPB, 0, stream>>>(ei, E, curs, col);

    k_wconv<<<dim3(48, 6), TPB, 0, stream>>>(W1, Wr1, W2, Wr2, Wmu, Wls,
                                             T1, Tr1, T2, Tr2, Tmu, Tls);

    const int np = (N + 127) / 128;   // 128-row pairs (two 64-row tiles per iteration)
    // layer 1: AB1 = x @ [W1|Wr1] (fused fp32->bf16 on A), B from L2.  No LDS ->
    // 4 blocks/CU by VGPR -> all np blocks resident (capacity 1024 > 782).
    k_gemm7<128, 192, 4, true><<<np, TPB, 0, stream>>>(x, T1, AB1, N, np);
    k_aggc<96, 16, false><<<(N + 15) / 16, TPB, 0, stream>>>(AB1, b1, dinv, dis, rowp, col, Hb1, N);

    // layer 2: AB2 = h1 @ [W2|Wr2]
    k_gemm7<96, 128, 4, false><<<np, TPB, 0, stream>>>(Hb1, T2, AB2, N, np);
    k_aggc<64, 8, true><<<(N + 31) / 32, TPB, 0, stream>>>(AB2, b2, dinv, dis, rowp, col, H2s, N);

    // heads: Zag = dis * (agg H2s + H2s), out = Zag @ [Wmu|Wls] + bias
    k_agghead<<<(N + 31) / 32, TPB, 0, stream>>>(H2s, dis, rowp, col, Zag, N);
    k_gemm_out7<<<np, TPB, 0, stream>>>(Zag, Tmu, bmu, bls, out, N, np);
}

// Round 6
// 303.121 us; speedup vs baseline: 1.1999x; 1.1999x over previous
//
#include <hip/hip_runtime.h>

#define TPB 256

typedef __attribute__((ext_vector_type(8))) short          bf8_t;   // 8 x bf16 (4 VGPRs)
typedef __attribute__((ext_vector_type(8))) unsigned short us8_t;
typedef __attribute__((ext_vector_type(4))) float          f4_t;
typedef __attribute__((ext_vector_type(4))) unsigned short us4_t;

__device__ __forceinline__ unsigned short f2bf(float f) {
    union { float f; unsigned u; } v; v.f = f;
    unsigned r = v.u + 0x7FFFu + ((v.u >> 16) & 1u);   // round-to-nearest-even
    return (unsigned short)(r >> 16);
}
__device__ __forceinline__ float bf2f(unsigned short u) {
    union { unsigned u; float f; } v; v.u = (unsigned)u << 16; return v.f;
}

// ---------------- graph build (CSR by dst, rebuilt every call) ----------------

__global__ void k_count(const int* __restrict__ ei, int E, int* __restrict__ cnt) {
    int e = blockIdx.x * TPB + threadIdx.x;
    if (e < E) atomicAdd(&cnt[ei[E + e]], 1);
}

__global__ void k_blocksum(const int* __restrict__ cnt, int n, int* __restrict__ bsum) {
    __shared__ int s[TPB];
    int t = threadIdx.x, i = blockIdx.x * TPB + t;
    s[t] = (i < n) ? cnt[i] : 0;
    __syncthreads();
    for (int off = TPB / 2; off > 0; off >>= 1) {
        if (t < off) s[t] += s[t + off];
        __syncthreads();
    }
    if (t == 0) bsum[blockIdx.x] = s[0];
}

__global__ void k_scan_bsum(int* __restrict__ bsum, int nb) {
    __shared__ int s[512];
    int t = threadIdx.x;
    int v = (t < nb) ? bsum[t] : 0;
    s[t] = v; __syncthreads();
    for (int off = 1; off < 512; off <<= 1) {
        int x = (t >= off) ? s[t - off] : 0;
        __syncthreads();
        s[t] += x;
        __syncthreads();
    }
    if (t < nb) bsum[t] = s[t] - v;   // exclusive block offsets
}

__global__ void k_rowptr(const int* __restrict__ cnt, const int* __restrict__ bsum, int n, int E,
                         int* __restrict__ rowptr, int* __restrict__ cursor,
                         float* __restrict__ dinv, float* __restrict__ dis) {
    __shared__ int s[TPB];
    int t = threadIdx.x, i = blockIdx.x * TPB + t;
    int v = (i < n) ? cnt[i] : 0;
    s[t] = v; __syncthreads();
    for (int off = 1; off < TPB; off <<= 1) {
        int x = (t >= off) ? s[t - off] : 0;
        __syncthreads();
        s[t] += x;
        __syncthreads();
    }
    if (i < n) {
        int start = bsum[blockIdx.x] + s[t] - v;
        rowptr[i] = start;
        cursor[i] = start;
        float d = (float)(v + 1);      // + self loop; deg >= 1 always
        dinv[i] = 1.0f / d;
        dis[i]  = rsqrtf(d);
    }
    if (i == 0) rowptr[n] = E;
}

__global__ void k_fill(const int* __restrict__ ei, int E,
                       int* __restrict__ cursor, int* __restrict__ col) {
    int e = blockIdx.x * TPB + threadIdx.x;
    if (e < E) {
        int src = ei[e], dst = ei[E + e];
        int p = atomicAdd(&cursor[dst], 1);
        col[p] = src;
    }
}

// ---------------- weight transpose+convert: T[m*K + k] = bf16(W[k*M + m]) ----------------
__global__ void k_wconv(const float* W1, const float* Wr1, const float* W2, const float* Wr2,
                        const float* Wmu, const float* Wls,
                        unsigned short* T1, unsigned short* Tr1, unsigned short* T2,
                        unsigned short* Tr2, unsigned short* Tmu, unsigned short* Tls) {
    const float* W; unsigned short* T; int K, M;
    switch (blockIdx.y) {
        case 0: W = W1;  T = T1;  K = 128; M = 96; break;
        case 1: W = Wr1; T = Tr1; K = 128; M = 96; break;
        case 2: W = W2;  T = T2;  K = 96;  M = 64; break;
        case 3: W = Wr2; T = Tr2; K = 96;  M = 64; break;
        case 4: W = Wmu; T = Tmu; K = 64;  M = 32; break;
        default:W = Wls; T = Tls; K = 64;  M = 32; break;
    }
    int idx = blockIdx.x * TPB + threadIdx.x;
    if (idx < K * M) {
        int m = idx / K, k = idx % K;
        T[idx] = f2bf(W[k * M + m]);
    }
}

// ---------------- MFMA GEMM v8: no LDS, B resident in REGISTERS -----------------------------
// Ledger across rounds: r0 (52KB LDS, 1 blk/CU): 42us latency-bound, write-amp 1.0x.
// r5 (no LDS, B re-read from L2 per tile): occ 2x but WRITE 180MB (4.7x) — per-tile B read
// stream evicted partially-written output lines (partial dirty evict + RFO refetch).
// v8: split output cols across the 4 waves -> per-wave B slice fits in registers
// (L1: 3cts*4frag*16B = 48 VGPR), loaded ONCE per block. Zero steady-state B traffic,
// no LDS, no barriers -> occupancy VGPR-limited (~4 blk/CU), store stream identical to
// r0's proven amp-1.0 epilogue (sequential cts, 2B stores). 16-row tiles (N%16==0),
// A shared by 4 waves via L1 broadcast (4x L1 reads, 1x L2/HBM).
template <int K, int M, int CTW, int MINW, bool AF32>
__global__ __launch_bounds__(TPB, MINW) void k_gemm8(const void* __restrict__ Av,
                                                     const unsigned short* __restrict__ WT,
                                                     unsigned short* __restrict__ Yb,
                                                     int n, int nt) {
    constexpr int KS = K / 32;

    int lane = threadIdx.x & 63;
    int wave = threadIdx.x >> 6;
    int quad = lane >> 4;
    int l15  = lane & 15;

    // B slice for this wave: cts [wave*CTW, wave*CTW+CTW), loaded once.
    bf8_t breg[CTW][KS];
#pragma unroll
    for (int j = 0; j < CTW; j++) {
        const unsigned short* bp = WT + (size_t)((wave * CTW + j) * 16 + l15) * K + quad * 8;
#pragma unroll
        for (int s = 0; s < KS; s++) breg[j][s] = *(const bf8_t*)(bp + s * 32);
    }

    for (int t = blockIdx.x; t < nt; t += gridDim.x) {
        int tbase = t * 16;
        int rA = tbase + l15; if (rA > n - 1) rA = n - 1;

        bf8_t a[KS];
        if (AF32) {
            const float* ap = (const float*)Av + (size_t)rA * K + quad * 8;
#pragma unroll
            for (int s = 0; s < KS; s++) {
                f4_t lo = *(const f4_t*)(ap + s * 32);
                f4_t hi = *(const f4_t*)(ap + s * 32 + 4);
                bf8_t tv;
                tv[0] = (short)f2bf(lo.x); tv[1] = (short)f2bf(lo.y);
                tv[2] = (short)f2bf(lo.z); tv[3] = (short)f2bf(lo.w);
                tv[4] = (short)f2bf(hi.x); tv[5] = (short)f2bf(hi.y);
                tv[6] = (short)f2bf(hi.z); tv[7] = (short)f2bf(hi.w);
                a[s] = tv;
            }
        } else {
            const unsigned short* ap = (const unsigned short*)Av + (size_t)rA * K + quad * 8;
#pragma unroll
            for (int s = 0; s < KS; s++) a[s] = *(const bf8_t*)(ap + s * 32);
        }

        int row = tbase + quad * 4;
#pragma unroll
        for (int j = 0; j < CTW; j++) {
            f4_t acc = {0.f, 0.f, 0.f, 0.f};
#pragma unroll
            for (int s = 0; s < KS; s++)
                acc = __builtin_amdgcn_mfma_f32_16x16x32_bf16(a[s], breg[j][s], acc, 0, 0, 0);
            int colg = (wave * CTW + j) * 16 + l15;
#pragma unroll
            for (int r = 0; r < 4; r++) {
                if (row + r < n) Yb[(size_t)(row + r) * M + colg] = f2bf(acc[r]);
            }
        }
    }
}

// ---------------- head GEMM v8: out = Z @ [Wmu|Wls] + bias, B in regs, no LDS --------------
__global__ __launch_bounds__(TPB, 8) void k_gemm_out8(const unsigned short* __restrict__ Z,
                                                      const unsigned short* __restrict__ WT,
                                                      const float* __restrict__ bmu,
                                                      const float* __restrict__ bls,
                                                      float* __restrict__ out, int n, int nt) {
    constexpr int K = 64, KS = 2;

    int lane = threadIdx.x & 63;
    int wave = threadIdx.x >> 6;
    int quad = lane >> 4;
    int l15  = lane & 15;

    bf8_t breg[KS];
    {
        const unsigned short* bp = WT + (size_t)(wave * 16 + l15) * K + quad * 8;
#pragma unroll
        for (int s = 0; s < KS; s++) breg[s] = *(const bf8_t*)(bp + s * 32);
    }
    int colg = wave * 16 + l15;
    float bias = (colg < 32) ? bmu[colg] : bls[colg - 32];
    float* dstc = (colg < 32) ? (out + colg) : (out + (size_t)n * 32 + (colg - 32));

    for (int t = blockIdx.x; t < nt; t += gridDim.x) {
        int tbase = t * 16;
        int rA = tbase + l15; if (rA > n - 1) rA = n - 1;
        const unsigned short* ap = Z + (size_t)rA * K + quad * 8;
        bf8_t a[KS];
#pragma unroll
        for (int s = 0; s < KS; s++) a[s] = *(const bf8_t*)(ap + s * 32);

        f4_t acc = {0.f, 0.f, 0.f, 0.f};
#pragma unroll
        for (int s = 0; s < KS; s++)
            acc = __builtin_amdgcn_mfma_f32_16x16x32_bf16(a[s], breg[s], acc, 0, 0, 0);

        int row = tbase + quad * 4;
#pragma unroll
        for (int r = 0; r < 4; r++) {
            if (row + r < n) dstc[(size_t)(row + r) * 32] = acc[r] + bias;
        }
    }
}

// ---------------- ClusterGCN aggregation (bf16 in/out) ----------------
// AB: n x 2*MF bf16 rows [y | r].  Hb[i] = bf16( s * relu( dinv[i]*(sum_{src->i} y[src] + y[i])
//                                                          + r[i] + bias ) ),  s = SCALE?dis[i]:1
template <int MF, int GRP, bool SCALE>
__global__ __launch_bounds__(TPB) void k_aggc(const unsigned short* __restrict__ AB,
                                              const float* __restrict__ bias,
                                              const float* __restrict__ dinv,
                                              const float* __restrict__ dis,
                                              const int* __restrict__ rowptr,
                                              const int* __restrict__ col,
                                              unsigned short* __restrict__ Hb, int n) {
    constexpr int LD = 2 * MF;
    int g = blockIdx.x * (TPB / GRP) + threadIdx.x / GRP;
    int l = threadIdx.x & (GRP - 1);
    if (g >= n) return;
    int c = l * 8;
    if (c >= MF) return;
    int r0 = rowptr[g], r1 = rowptr[g + 1];
    float acc[8];
    {
        bf8_t v = *(const bf8_t*)(AB + (size_t)g * LD + c);
#pragma unroll
        for (int j = 0; j < 8; j++) acc[j] = bf2f((unsigned short)v[j]);
    }
    int e = r0;
    for (; e + 4 <= r1; e += 4) {          // 4-way MLP unroll
        int s0 = col[e], s1 = col[e + 1], s2 = col[e + 2], s3 = col[e + 3];
        bf8_t v0 = *(const bf8_t*)(AB + (size_t)s0 * LD + c);
        bf8_t v1 = *(const bf8_t*)(AB + (size_t)s1 * LD + c);
        bf8_t v2 = *(const bf8_t*)(AB + (size_t)s2 * LD + c);
        bf8_t v3 = *(const bf8_t*)(AB + (size_t)s3 * LD + c);
#pragma unroll
        for (int j = 0; j < 8; j++)
            acc[j] += (bf2f((unsigned short)v0[j]) + bf2f((unsigned short)v1[j]))
                    + (bf2f((unsigned short)v2[j]) + bf2f((unsigned short)v3[j]));
    }
    for (; e < r1; ++e) {
        int s = col[e];
        bf8_t v = *(const bf8_t*)(AB + (size_t)s * LD + c);
#pragma unroll
        for (int j = 0; j < 8; j++) acc[j] += bf2f((unsigned short)v[j]);
    }
    float di = dinv[g];
    float sc = SCALE ? dis[g] : 1.0f;
    bf8_t rr = *(const bf8_t*)(AB + (size_t)g * LD + MF + c);
    us8_t o;
#pragma unroll
    for (int j = 0; j < 8; j++) {
        float h = fmaxf(acc[j] * di + bf2f((unsigned short)rr[j]) + bias[c + j], 0.f);
        o[j] = f2bf(SCALE ? sc * h : h);
    }
    *(us8_t*)(Hb + (size_t)g * MF + c) = o;
}

// ---------------- head aggregation: Z[g] = bf16( dis[g] * (sum_{src->g} H2s[src] + H2s[g]) ) ----
// H2s rows are pre-scaled by dis (written by layer-2 epilogue), so no per-edge dis load.
__global__ __launch_bounds__(TPB) void k_agghead(const unsigned short* __restrict__ H2s,
                                                 const float* __restrict__ dis,
                                                 const int* __restrict__ rowptr,
                                                 const int* __restrict__ col,
                                                 unsigned short* __restrict__ Z, int n) {
    const int GRP = 8;
    int g = blockIdx.x * (TPB / GRP) + threadIdx.x / GRP;
    int l = threadIdx.x & (GRP - 1);
    if (g >= n) return;
    int c = l * 8;
    int r0 = rowptr[g], r1 = rowptr[g + 1];
    float acc[8];
    {
        bf8_t v = *(const bf8_t*)(H2s + (size_t)g * 64 + c);
#pragma unroll
        for (int j = 0; j < 8; j++) acc[j] = bf2f((unsigned short)v[j]);
    }
    int e = r0;
    for (; e + 4 <= r1; e += 4) {
        int s0 = col[e], s1 = col[e + 1], s2 = col[e + 2], s3 = col[e + 3];
        bf8_t v0 = *(const bf8_t*)(H2s + (size_t)s0 * 64 + c);
        bf8_t v1 = *(const bf8_t*)(H2s + (size_t)s1 * 64 + c);
        bf8_t v2 = *(const bf8_t*)(H2s + (size_t)s2 * 64 + c);
        bf8_t v3 = *(const bf8_t*)(H2s + (size_t)s3 * 64 + c);
#pragma unroll
        for (int j = 0; j < 8; j++)
            acc[j] += (bf2f((unsigned short)v0[j]) + bf2f((unsigned short)v1[j]))
                    + (bf2f((unsigned short)v2[j]) + bf2f((unsigned short)v3[j]));
    }
    for (; e < r1; ++e) {
        int s = col[e];
        bf8_t v = *(const bf8_t*)(H2s + (size_t)s * 64 + c);
#pragma unroll
        for (int j = 0; j < 8; j++) acc[j] += bf2f((unsigned short)v[j]);
    }
    float dg = dis[g];
    us8_t o;
#pragma unroll
    for (int j = 0; j < 8; j++) o[j] = f2bf(dg * acc[j]);
    *(us8_t*)(Z + (size_t)g * 64 + c) = o;
}

// ---------------- launch ----------------

extern "C" void kernel_launch(void* const* d_in, const int* in_sizes, int n_in,
                              void* d_out, int out_size, void* d_ws, size_t ws_size,
                              hipStream_t stream) {
    const float* x   = (const float*)d_in[0];
    const int*   ei  = (const int*)d_in[1];
    const float* W1  = (const float*)d_in[2];
    const float* b1  = (const float*)d_in[3];
    const float* Wr1 = (const float*)d_in[4];
    const float* W2  = (const float*)d_in[5];
    const float* b2  = (const float*)d_in[6];
    const float* Wr2 = (const float*)d_in[7];
    const float* Wmu = (const float*)d_in[8];
    const float* bmu = (const float*)d_in[9];
    const float* Wls = (const float*)d_in[10];
    const float* bls = (const float*)d_in[11];
    float* out = (float*)d_out;

    const int IN = 128, L1F = 96, L2F = 64;
    const int N = in_sizes[0] / IN;
    const int E = in_sizes[1] / 2;

    char* ws = (char*)d_ws;
    size_t off = 0;
    auto alloc = [&](size_t b) { size_t r = off; off += (b + 255) & ~(size_t)255; return r; };

    const int nb = (N + TPB - 1) / TPB;
    int*   cnt  = (int*)(ws + alloc((size_t)N * 4));
    int*   bsum = (int*)(ws + alloc((size_t)nb * 4));
    int*   rowp = (int*)(ws + alloc((size_t)(N + 1) * 4));
    int*   curs = (int*)(ws + alloc((size_t)N * 4));
    int*   col  = (int*)(ws + alloc((size_t)E * 4));
    float* dinv = (float*)(ws + alloc((size_t)N * 4));
    float* dis  = (float*)(ws + alloc((size_t)N * 4));
    // weight blocks allocated contiguously -> concatenated [W|Wr] views (all sizes %256==0)
    unsigned short* T1  = (unsigned short*)(ws + alloc((size_t)IN  * L1F * 2));
    unsigned short* Tr1 = (unsigned short*)(ws + alloc((size_t)IN  * L1F * 2));
    unsigned short* T2  = (unsigned short*)(ws + alloc((size_t)L1F * L2F * 2));
    unsigned short* Tr2 = (unsigned short*)(ws + alloc((size_t)L1F * L2F * 2));
    unsigned short* Tmu = (unsigned short*)(ws + alloc((size_t)L2F * 32 * 2));
    unsigned short* Tls = (unsigned short*)(ws + alloc((size_t)L2F * 32 * 2));
    unsigned short* AB1 = (unsigned short*)(ws + alloc((size_t)N * 2 * L1F * 2)); // N x 192 bf16
    unsigned short* AB2 = (unsigned short*)(ws + alloc((size_t)N * 2 * L2F * 2)); // N x 128 bf16
    unsigned short* Hb1 = (unsigned short*)(ws + alloc((size_t)N * L1F * 2));     // relu'd h1
    unsigned short* H2s = (unsigned short*)(ws + alloc((size_t)N * L2F * 2));     // dis-scaled h2
    unsigned short* Zag = (unsigned short*)(ws + alloc((size_t)N * L2F * 2));     // aggregated head input

    hipMemsetAsync(cnt, 0, (size_t)N * 4, stream);

    dim3 eg((E + TPB - 1) / TPB);
    k_count<<<eg, TPB, 0, stream>>>(ei, E, cnt);
    k_blocksum<<<nb, TPB, 0, stream>>>(cnt, N, bsum);
    k_scan_bsum<<<1, 512, 0, stream>>>(bsum, nb);
    k_rowptr<<<nb, TPB, 0, stream>>>(cnt, bsum, N, E, rowp, curs, dinv, dis);
    k_fill<<<eg, TPB, 0, stream>>>(ei, E, curs, col);

    k_wconv<<<dim3(48, 6), TPB, 0, stream>>>(W1, Wr1, W2, Wr2, Wmu, Wls,
                                             T1, Tr1, T2, Tr2, Tmu, Tls);

    const int nt = (N + 15) / 16;     // 16-row tiles (N=100000 -> exactly 6250)
    const int gg = 2048;              // ~4 blocks/CU resident, grid-stride ~3 tiles each
    // layer 1: AB1 = x @ [W1|Wr1] (fused fp32->bf16 on A). CTW=3 (12 cts / 4 waves).
    k_gemm8<128, 192, 3, 4, true><<<gg, TPB, 0, stream>>>(x, T1, AB1, N, nt);
    k_aggc<96, 16, false><<<(N + 15) / 16, TPB, 0, stream>>>(AB1, b1, dinv, dis, rowp, col, Hb1, N);

    // layer 2: AB2 = h1 @ [W2|Wr2]. CTW=2 (8 cts / 4 waves).
    k_gemm8<96, 128, 2, 6, false><<<gg, TPB, 0, stream>>>(Hb1, T2, AB2, N, nt);
    k_aggc<64, 8, true><<<(N + 31) / 32, TPB, 0, stream>>>(AB2, b2, dinv, dis, rowp, col, H2s, N);

    // heads: Zag = dis * (agg H2s + H2s), out = Zag @ [Wmu|Wls] + bias
    k_agghead<<<(N + 31) / 32, TPB, 0, stream>>>(H2s, dis, rowp, col, Zag, N);
    k_gemm_out8<<<gg, TPB, 0, stream>>>(Zag, Tmu, bmu, bls, out, N, nt);
}

// Round 7
// 280.445 us; speedup vs baseline: 1.2970x; 1.0809x over previous
//
#include <hip/hip_runtime.h>

#define TPB 256

typedef __attribute__((ext_vector_type(8))) short          bf8_t;   // 8 x bf16 (4 VGPRs)
typedef __attribute__((ext_vector_type(8))) unsigned short us8_t;
typedef __attribute__((ext_vector_type(4))) float          f4_t;
typedef __attribute__((ext_vector_type(4))) unsigned short us4_t;

__device__ __forceinline__ unsigned short f2bf(float f) {
    union { float f; unsigned u; } v; v.f = f;
    unsigned r = v.u + 0x7FFFu + ((v.u >> 16) & 1u);   // round-to-nearest-even
    return (unsigned short)(r >> 16);
}
__device__ __forceinline__ float bf2f(unsigned short u) {
    union { unsigned u; float f; } v; v.u = (unsigned)u << 16; return v.f;
}

// ---------------- graph build (CSR by dst, rebuilt every call) ----------------

__global__ void k_count(const int* __restrict__ ei, int E, int* __restrict__ cnt) {
    int e = blockIdx.x * TPB + threadIdx.x;
    if (e < E) atomicAdd(&cnt[ei[E + e]], 1);
}

__global__ void k_blocksum(const int* __restrict__ cnt, int n, int* __restrict__ bsum) {
    __shared__ int s[TPB];
    int t = threadIdx.x, i = blockIdx.x * TPB + t;
    s[t] = (i < n) ? cnt[i] : 0;
    __syncthreads();
    for (int off = TPB / 2; off > 0; off >>= 1) {
        if (t < off) s[t] += s[t + off];
        __syncthreads();
    }
    if (t == 0) bsum[blockIdx.x] = s[0];
}

__global__ void k_scan_bsum(int* __restrict__ bsum, int nb) {
    __shared__ int s[512];
    int t = threadIdx.x;
    int v = (t < nb) ? bsum[t] : 0;
    s[t] = v; __syncthreads();
    for (int off = 1; off < 512; off <<= 1) {
        int x = (t >= off) ? s[t - off] : 0;
        __syncthreads();
        s[t] += x;
        __syncthreads();
    }
    if (t < nb) bsum[t] = s[t] - v;   // exclusive block offsets
}

__global__ void k_rowptr(const int* __restrict__ cnt, const int* __restrict__ bsum, int n, int E,
                         int* __restrict__ rowptr, int* __restrict__ cursor,
                         float* __restrict__ dinv, float* __restrict__ dis) {
    __shared__ int s[TPB];
    int t = threadIdx.x, i = blockIdx.x * TPB + t;
    int v = (i < n) ? cnt[i] : 0;
    s[t] = v; __syncthreads();
    for (int off = 1; off < TPB; off <<= 1) {
        int x = (t >= off) ? s[t - off] : 0;
        __syncthreads();
        s[t] += x;
        __syncthreads();
    }
    if (i < n) {
        int start = bsum[blockIdx.x] + s[t] - v;
        rowptr[i] = start;
        cursor[i] = start;
        float d = (float)(v + 1);      // + self loop; deg >= 1 always
        dinv[i] = 1.0f / d;
        dis[i]  = rsqrtf(d);
    }
    if (i == 0) rowptr[n] = E;
}

__global__ void k_fill(const int* __restrict__ ei, int E,
                       int* __restrict__ cursor, int* __restrict__ col) {
    int e = blockIdx.x * TPB + threadIdx.x;
    if (e < E) {
        int src = ei[e], dst = ei[E + e];
        int p = atomicAdd(&cursor[dst], 1);
        col[p] = src;
    }
}

// ---------------- weight transpose+convert: T[m*K + k] = bf16(W[k*M + m]) ----------------
__global__ void k_wconv(const float* W1, const float* Wr1, const float* W2, const float* Wr2,
                        const float* Wmu, const float* Wls,
                        unsigned short* T1, unsigned short* Tr1, unsigned short* T2,
                        unsigned short* Tr2, unsigned short* Tmu, unsigned short* Tls) {
    const float* W; unsigned short* T; int K, M;
    switch (blockIdx.y) {
        case 0: W = W1;  T = T1;  K = 128; M = 96; break;
        case 1: W = Wr1; T = Tr1; K = 128; M = 96; break;
        case 2: W = W2;  T = T2;  K = 96;  M = 64; break;
        case 3: W = Wr2; T = Tr2; K = 96;  M = 64; break;
        case 4: W = Wmu; T = Tmu; K = 64;  M = 32; break;
        default:W = Wls; T = Tls; K = 64;  M = 32; break;
    }
    int idx = blockIdx.x * TPB + threadIdx.x;
    if (idx < K * M) {
        int m = idx / K, k = idx % K;
        T[idx] = f2bf(W[k * M + m]);
    }
}

// ---------------- MFMA GEMM (r0-measured-best form): LDS-staged B, 64-row tiles ------------
// Component ledger: this exact kernel measured 42.0 us / FETCH 25.4 / WRITE 37.5 (amp 1.0)
// at grid 768 in round 0 — best of all 5 GEMM structures tried (ILP/no-LDS/reg-B all 42-49).
template <int K, int M, bool AF32>
__global__ __launch_bounds__(TPB) void k_gemm3(const void* __restrict__ Av,
                                               const unsigned short* __restrict__ WT,
                                               unsigned short* __restrict__ Yb,
                                               int n, int nt) {
    constexpr int KS = K / 32;
    constexpr int ST = K + 8;
    __shared__ unsigned short Bs[M * ST];
    for (int i = threadIdx.x * 8; i < M * K; i += TPB * 8) {
        int m = i / K, k = i - m * K;
        *(us8_t*)(Bs + m * ST + k) = *(const us8_t*)(WT + i);
    }
    __syncthreads();

    int lane = threadIdx.x & 63;
    int wave = threadIdx.x >> 6;
    int quad = lane >> 4;
    int l15  = lane & 15;

    for (int tile = blockIdx.x; tile < nt; tile += gridDim.x) {
        int base = tile * 64 + wave * 16;
        int rA = base + l15; if (rA > n - 1) rA = n - 1;

        bf8_t a[KS];
        if (AF32) {
            const float* ap = (const float*)Av + (size_t)rA * K + quad * 8;
#pragma unroll
            for (int s = 0; s < KS; s++) {
                f4_t lo = *(const f4_t*)(ap + s * 32);
                f4_t hi = *(const f4_t*)(ap + s * 32 + 4);
                bf8_t t;
                t[0] = (short)f2bf(lo.x); t[1] = (short)f2bf(lo.y);
                t[2] = (short)f2bf(lo.z); t[3] = (short)f2bf(lo.w);
                t[4] = (short)f2bf(hi.x); t[5] = (short)f2bf(hi.y);
                t[6] = (short)f2bf(hi.z); t[7] = (short)f2bf(hi.w);
                a[s] = t;
            }
        } else {
            const unsigned short* ap = (const unsigned short*)Av + (size_t)rA * K + quad * 8;
#pragma unroll
            for (int s = 0; s < KS; s++) a[s] = *(const bf8_t*)(ap + s * 32);
        }

        int row = base + quad * 4;
#pragma unroll
        for (int ct = 0; ct < M / 16; ct++) {
            const unsigned short* bp = Bs + (ct * 16 + l15) * ST + quad * 8;
            f4_t acc = {0.f, 0.f, 0.f, 0.f};
#pragma unroll
            for (int s = 0; s < KS; s++) {
                bf8_t b = *(const bf8_t*)(bp + s * 32);
                acc = __builtin_amdgcn_mfma_f32_16x16x32_bf16(a[s], b, acc, 0, 0, 0);
            }
            int colg = ct * 16 + l15;
#pragma unroll
            for (int r = 0; r < 4; r++) {
                if (row + r < n) Yb[(size_t)(row + r) * M + colg] = f2bf(acc[r]);
            }
        }
    }
}

// ---------------- fuse1: ClusterGCN-agg(layer1) + GEMM(layer2) per 16-row tile --------------
// Phase 1: h1[g] = relu(dinv*agg(y1) + r1 + b1) -> LDS (double-buffered, pad 104).
// Phase 2: AB2[tile rows] = h1_tile @ [W2|Wr2] with W2 slices register-resident per wave.
// Hb1 intermediate (19.2 MB write + 19.2 MB read + 1 dispatch) eliminated.
__global__ __launch_bounds__(TPB, 4) void k_fuse1(const unsigned short* __restrict__ AB,
                                                  const unsigned short* __restrict__ WT2,
                                                  const float* __restrict__ bias,
                                                  const float* __restrict__ dinv,
                                                  const int* __restrict__ rowptr,
                                                  const int* __restrict__ col,
                                                  unsigned short* __restrict__ AB2,
                                                  int n, int nt) {
    constexpr int LDA = 192, MF = 96, ST1 = 104, KS = 3, M2 = 128;
    __shared__ unsigned short Hs[2][16 * ST1];

    int t = threadIdx.x;
    int lane = t & 63, wave = t >> 6, quad = lane >> 4, l15 = lane & 15;

    // register-resident B: wave w owns output cols [w*32, w*32+32) = cts {2w, 2w+1}
    bf8_t breg[2][KS];
#pragma unroll
    for (int j = 0; j < 2; j++) {
        const unsigned short* bp = WT2 + (size_t)((wave * 2 + j) * 16 + l15) * 96 + quad * 8;
#pragma unroll
        for (int s = 0; s < KS; s++) breg[j][s] = *(const bf8_t*)(bp + s * 32);
    }

    int gl = t >> 4;          // tile-local row 0..15
    int cg = t & 15;          // col-group; active if cg < 12
    int c  = cg * 8;
    bool p1act = (c < MF);

    int p = 0;
    for (int tile = blockIdx.x; tile < nt; tile += gridDim.x, p ^= 1) {
        int tbase = tile * 16;
        if (p1act) {                                  // no early return: barrier below
            int g = tbase + gl; if (g > n - 1) g = n - 1;
            int r0 = rowptr[g], r1 = rowptr[g + 1];
            float acc[8];
            {
                bf8_t v = *(const bf8_t*)(AB + (size_t)g * LDA + c);
#pragma unroll
                for (int j = 0; j < 8; j++) acc[j] = bf2f((unsigned short)v[j]);
            }
            int e = r0;
            for (; e + 4 <= r1; e += 4) {
                int s0 = col[e], s1 = col[e + 1], s2 = col[e + 2], s3 = col[e + 3];
                bf8_t v0 = *(const bf8_t*)(AB + (size_t)s0 * LDA + c);
                bf8_t v1 = *(const bf8_t*)(AB + (size_t)s1 * LDA + c);
                bf8_t v2 = *(const bf8_t*)(AB + (size_t)s2 * LDA + c);
                bf8_t v3 = *(const bf8_t*)(AB + (size_t)s3 * LDA + c);
#pragma unroll
                for (int j = 0; j < 8; j++)
                    acc[j] += (bf2f((unsigned short)v0[j]) + bf2f((unsigned short)v1[j]))
                            + (bf2f((unsigned short)v2[j]) + bf2f((unsigned short)v3[j]));
            }
            for (; e < r1; ++e) {
                int s = col[e];
                bf8_t v = *(const bf8_t*)(AB + (size_t)s * LDA + c);
#pragma unroll
                for (int j = 0; j < 8; j++) acc[j] += bf2f((unsigned short)v[j]);
            }
            float di = dinv[g];
            bf8_t rr = *(const bf8_t*)(AB + (size_t)g * LDA + MF + c);
            us8_t o;
#pragma unroll
            for (int j = 0; j < 8; j++)
                o[j] = f2bf(fmaxf(acc[j] * di + bf2f((unsigned short)rr[j]) + bias[c + j], 0.f));
            *(us8_t*)(&Hs[p][gl * ST1 + c]) = o;
        }
        __syncthreads();

        // phase 2: 16 x 128 GEMM from LDS h1 tile
        int row = tbase + quad * 4;
#pragma unroll
        for (int j = 0; j < 2; j++) {
            const unsigned short* apl = &Hs[p][l15 * ST1 + quad * 8];
            f4_t acc2 = {0.f, 0.f, 0.f, 0.f};
#pragma unroll
            for (int s = 0; s < KS; s++) {
                bf8_t a = *(const bf8_t*)(apl + s * 32);
                acc2 = __builtin_amdgcn_mfma_f32_16x16x32_bf16(a, breg[j][s], acc2, 0, 0, 0);
            }
            int colg = (wave * 2 + j) * 16 + l15;
#pragma unroll
            for (int r = 0; r < 4; r++) {
                if (row + r < n) AB2[(size_t)(row + r) * M2 + colg] = f2bf(acc2[r]);
            }
        }
        // no trailing barrier: double buffer; next phase-1 writes Hs[p^1]
    }
}

// ---------------- aggc (standalone, layer 2): H2s = dis * relu(dinv*agg(y2) + r2 + b2) -------
template <int MF, int GRP, bool SCALE>
__global__ __launch_bounds__(TPB) void k_aggc(const unsigned short* __restrict__ AB,
                                              const float* __restrict__ bias,
                                              const float* __restrict__ dinv,
                                              const float* __restrict__ dis,
                                              const int* __restrict__ rowptr,
                                              const int* __restrict__ col,
                                              unsigned short* __restrict__ Hb, int n) {
    constexpr int LD = 2 * MF;
    int g = blockIdx.x * (TPB / GRP) + threadIdx.x / GRP;
    int l = threadIdx.x & (GRP - 1);
    if (g >= n) return;
    int c = l * 8;
    if (c >= MF) return;
    int r0 = rowptr[g], r1 = rowptr[g + 1];
    float acc[8];
    {
        bf8_t v = *(const bf8_t*)(AB + (size_t)g * LD + c);
#pragma unroll
        for (int j = 0; j < 8; j++) acc[j] = bf2f((unsigned short)v[j]);
    }
    int e = r0;
    for (; e + 4 <= r1; e += 4) {
        int s0 = col[e], s1 = col[e + 1], s2 = col[e + 2], s3 = col[e + 3];
        bf8_t v0 = *(const bf8_t*)(AB + (size_t)s0 * LD + c);
        bf8_t v1 = *(const bf8_t*)(AB + (size_t)s1 * LD + c);
        bf8_t v2 = *(const bf8_t*)(AB + (size_t)s2 * LD + c);
        bf8_t v3 = *(const bf8_t*)(AB + (size_t)s3 * LD + c);
#pragma unroll
        for (int j = 0; j < 8; j++)
            acc[j] += (bf2f((unsigned short)v0[j]) + bf2f((unsigned short)v1[j]))
                    + (bf2f((unsigned short)v2[j]) + bf2f((unsigned short)v3[j]));
    }
    for (; e < r1; ++e) {
        int s = col[e];
        bf8_t v = *(const bf8_t*)(AB + (size_t)s * LD + c);
#pragma unroll
        for (int j = 0; j < 8; j++) acc[j] += bf2f((unsigned short)v[j]);
    }
    float di = dinv[g];
    float sc = SCALE ? dis[g] : 1.0f;
    bf8_t rr = *(const bf8_t*)(AB + (size_t)g * LD + MF + c);
    us8_t o;
#pragma unroll
    for (int j = 0; j < 8; j++) {
        float h = fmaxf(acc[j] * di + bf2f((unsigned short)rr[j]) + bias[c + j], 0.f);
        o[j] = f2bf(SCALE ? sc * h : h);
    }
    *(us8_t*)(Hb + (size_t)g * MF + c) = o;
}

// ---------------- fuse2: head aggregation + head GEMM per 32-row tile -----------------------
// Phase 1: z[g] = dis[g] * (agg(H2s) + H2s[g]) -> LDS (double-buffered, pad 72).
// Phase 2: out rows = z_tile @ [Wmu|Wls] + bias (W in regs, wave w -> ct w).
// Zag intermediate (12.8 MB write + 12.8 MB read + 1 dispatch) eliminated.
__global__ __launch_bounds__(TPB, 4) void k_fuse2(const unsigned short* __restrict__ H2s,
                                                  const unsigned short* __restrict__ WTo,
                                                  const float* __restrict__ bmu,
                                                  const float* __restrict__ bls,
                                                  const float* __restrict__ dis,
                                                  const int* __restrict__ rowptr,
                                                  const int* __restrict__ col,
                                                  float* __restrict__ out, int n, int nt) {
    constexpr int ST2 = 72, KS = 2;
    __shared__ unsigned short Zs[2][32 * ST2];

    int t = threadIdx.x;
    int lane = t & 63, wave = t >> 6, quad = lane >> 4, l15 = lane & 15;

    bf8_t breg[KS];
    {
        const unsigned short* bp = WTo + (size_t)(wave * 16 + l15) * 64 + quad * 8;
#pragma unroll
        for (int s = 0; s < KS; s++) breg[s] = *(const bf8_t*)(bp + s * 32);
    }
    int colg = wave * 16 + l15;
    float bias = (colg < 32) ? bmu[colg] : bls[colg - 32];
    float* dstc = (colg < 32) ? (out + colg) : (out + (size_t)n * 32 + (colg - 32));

    int gl = t >> 3;          // tile-local row 0..31
    int c  = (t & 7) * 8;     // col 0..56 (all 256 threads active)

    int p = 0;
    for (int tile = blockIdx.x; tile < nt; tile += gridDim.x, p ^= 1) {
        int tbase = tile * 32;
        {
            int g = tbase + gl; if (g > n - 1) g = n - 1;
            int r0 = rowptr[g], r1 = rowptr[g + 1];
            float acc[8];
            {
                bf8_t v = *(const bf8_t*)(H2s + (size_t)g * 64 + c);
#pragma unroll
                for (int j = 0; j < 8; j++) acc[j] = bf2f((unsigned short)v[j]);
            }
            int e = r0;
            for (; e + 4 <= r1; e += 4) {
                int s0 = col[e], s1 = col[e + 1], s2 = col[e + 2], s3 = col[e + 3];
                bf8_t v0 = *(const bf8_t*)(H2s + (size_t)s0 * 64 + c);
                bf8_t v1 = *(const bf8_t*)(H2s + (size_t)s1 * 64 + c);
                bf8_t v2 = *(const bf8_t*)(H2s + (size_t)s2 * 64 + c);
                bf8_t v3 = *(const bf8_t*)(H2s + (size_t)s3 * 64 + c);
#pragma unroll
                for (int j = 0; j < 8; j++)
                    acc[j] += (bf2f((unsigned short)v0[j]) + bf2f((unsigned short)v1[j]))
                            + (bf2f((unsigned short)v2[j]) + bf2f((unsigned short)v3[j]));
            }
            for (; e < r1; ++e) {
                int s = col[e];
                bf8_t v = *(const bf8_t*)(H2s + (size_t)s * 64 + c);
#pragma unroll
                for (int j = 0; j < 8; j++) acc[j] += bf2f((unsigned short)v[j]);
            }
            float dg = dis[g];
            us8_t o;
#pragma unroll
            for (int j = 0; j < 8; j++) o[j] = f2bf(dg * acc[j]);
            *(us8_t*)(&Zs[p][gl * ST2 + c]) = o;
        }
        __syncthreads();

        // phase 2: two 16-row sub-tiles, ct = wave
#pragma unroll
        for (int st = 0; st < 2; st++) {
            const unsigned short* apl = &Zs[p][(st * 16 + l15) * ST2 + quad * 8];
            bf8_t a[KS];
#pragma unroll
            for (int s = 0; s < KS; s++) a[s] = *(const bf8_t*)(apl + s * 32);
            f4_t acc = {0.f, 0.f, 0.f, 0.f};
#pragma unroll
            for (int s = 0; s < KS; s++)
                acc = __builtin_amdgcn_mfma_f32_16x16x32_bf16(a[s], breg[s], acc, 0, 0, 0);
            int row = tbase + st * 16 + quad * 4;
#pragma unroll
            for (int r = 0; r < 4; r++) {
                if (row + r < n) dstc[(size_t)(row + r) * 32] = acc[r] + bias;
            }
        }
    }
}

// ---------------- launch ----------------

extern "C" void kernel_launch(void* const* d_in, const int* in_sizes, int n_in,
                              void* d_out, int out_size, void* d_ws, size_t ws_size,
                              hipStream_t stream) {
    const float* x   = (const float*)d_in[0];
    const int*   ei  = (const int*)d_in[1];
    const float* W1  = (const float*)d_in[2];
    const float* b1  = (const float*)d_in[3];
    const float* Wr1 = (const float*)d_in[4];
    const float* W2  = (const float*)d_in[5];
    const float* b2  = (const float*)d_in[6];
    const float* Wr2 = (const float*)d_in[7];
    const float* Wmu = (const float*)d_in[8];
    const float* bmu = (const float*)d_in[9];
    const float* Wls = (const float*)d_in[10];
    const float* bls = (const float*)d_in[11];
    float* out = (float*)d_out;

    const int IN = 128, L1F = 96, L2F = 64;
    const int N = in_sizes[0] / IN;
    const int E = in_sizes[1] / 2;

    char* ws = (char*)d_ws;
    size_t off = 0;
    auto alloc = [&](size_t b) { size_t r = off; off += (b + 255) & ~(size_t)255; return r; };

    const int nb = (N + TPB - 1) / TPB;
    int*   cnt  = (int*)(ws + alloc((size_t)N * 4));
    int*   bsum = (int*)(ws + alloc((size_t)nb * 4));
    int*   rowp = (int*)(ws + alloc((size_t)(N + 1) * 4));
    int*   curs = (int*)(ws + alloc((size_t)N * 4));
    int*   col  = (int*)(ws + alloc((size_t)E * 4));
    float* dinv = (float*)(ws + alloc((size_t)N * 4));
    float* dis  = (float*)(ws + alloc((size_t)N * 4));
    // weight blocks allocated contiguously -> concatenated [W|Wr] views (all sizes %256==0)
    unsigned short* T1  = (unsigned short*)(ws + alloc((size_t)IN  * L1F * 2));
    unsigned short* Tr1 = (unsigned short*)(ws + alloc((size_t)IN  * L1F * 2));
    unsigned short* T2  = (unsigned short*)(ws + alloc((size_t)L1F * L2F * 2));
    unsigned short* Tr2 = (unsigned short*)(ws + alloc((size_t)L1F * L2F * 2));
    unsigned short* Tmu = (unsigned short*)(ws + alloc((size_t)L2F * 32 * 2));
    unsigned short* Tls = (unsigned short*)(ws + alloc((size_t)L2F * 32 * 2));
    unsigned short* AB1 = (unsigned short*)(ws + alloc((size_t)N * 2 * L1F * 2)); // N x 192 bf16
    unsigned short* AB2 = (unsigned short*)(ws + alloc((size_t)N * 2 * L2F * 2)); // N x 128 bf16
    unsigned short* H2s = (unsigned short*)(ws + alloc((size_t)N * L2F * 2));     // dis-scaled h2
    (void)Tr1; (void)Tr2; (void)Tls;

    hipMemsetAsync(cnt, 0, (size_t)N * 4, stream);

    dim3 eg((E + TPB - 1) / TPB);
    k_count<<<eg, TPB, 0, stream>>>(ei, E, cnt);
    k_blocksum<<<nb, TPB, 0, stream>>>(cnt, N, bsum);
    k_scan_bsum<<<1, 512, 0, stream>>>(bsum, nb);
    k_rowptr<<<nb, TPB, 0, stream>>>(cnt, bsum, N, E, rowp, curs, dinv, dis);
    k_fill<<<eg, TPB, 0, stream>>>(ei, E, curs, col);

    k_wconv<<<dim3(48, 6), TPB, 0, stream>>>(W1, Wr1, W2, Wr2, Wmu, Wls,
                                             T1, Tr1, T2, Tr2, Tmu, Tls);

    // layer 1 GEMM: AB1 = x @ [W1|Wr1]  (r0-measured-best config: 42 us, amp 1.0)
    const int nt64 = (N + 63) / 64;
    k_gemm3<128, 192, true><<<768, TPB, 0, stream>>>(x, T1, AB1, N, nt64);

    // fused: aggc(layer1) + GEMM(layer2) -> AB2   (Hb1 eliminated)
    const int nt16 = (N + 15) / 16;
    k_fuse1<<<2048, TPB, 0, stream>>>(AB1, T2, b1, dinv, rowp, col, AB2, N, nt16);

    // layer 2 aggregation: H2s = dis * relu(dinv*agg + r + b2)
    k_aggc<64, 8, true><<<(N + 31) / 32, TPB, 0, stream>>>(AB2, b2, dinv, dis, rowp, col, H2s, N);

    // fused: head aggregation + head GEMM -> out   (Zag eliminated)
    const int nt32 = (N + 31) / 32;
    k_fuse2<<<2048, TPB, 0, stream>>>(H2s, Tmu, bmu, bls, dis, rowp, col, out, N, nt32);
}